// Round 14
// baseline (151.922 us; speedup 1.0000x reference)
//
#include <hip/hip_runtime.h>
#include <hip/hip_bf16.h>
#include <cfloat>
#include <cmath>

#define B_ 4
#define S_ 1024
#define C_ 4096
#define K_ 64
#define D_ 256
#define NC 4160   // C_ + K_  (= 260 groups of 16)
#define TOPN 16
#define LTOP 8    // per-lane list depth (statistically exact superset)
#define CANDK 128 // 8 splits x 16 keys; refine narrows to 32 by key

typedef __attribute__((ext_vector_type(8))) short short8;
typedef __attribute__((ext_vector_type(4))) float f32x4;

#define UMIN(a, b) ((a) < (b) ? (a) : (b))
#define UMAX(a, b) ((a) < (b) ? (b) : (a))

// ---------------- fused prep: proj64 (blocks 0..255) + cvt/norm ctx (256..4351) + mem (4352..4415) ----------------
__global__ __launch_bounds__(256) void prep_kernel(
    const float* __restrict__ q, const float* __restrict__ W,
    const float* __restrict__ bias, double* __restrict__ qp64,
    __hip_bfloat16* __restrict__ qpb,
    const float* __restrict__ ctx, const float* __restrict__ mem,
    unsigned short* __restrict__ candb, float* __restrict__ cn)
{
  __shared__ alignas(16) float As[64][36];
  __shared__ alignas(16) float Ws[64][36];
  const int blk = blockIdx.x;
  const int tid = threadIdx.x;

  if (blk < 256) {   // ---- projection ----
    const int m0 = (blk & 63) * 64;
    const int n0 = (blk >> 6) * 64;
    const int tx = tid & 15;
    const int ty = tid >> 4;
    const int lr = tid >> 3;
    const int lk = (tid & 7) * 4;
    double acc[4][4] = {};
    for (int k0 = 0; k0 < D_; k0 += 32) {
      __syncthreads();
      {
        float4 a0 = *(const float4*)&q[(size_t)(m0 + lr) * D_ + k0 + lk];
        float4 a1 = *(const float4*)&q[(size_t)(m0 + lr + 32) * D_ + k0 + lk];
        *(float4*)&As[lr][lk] = a0;
        *(float4*)&As[lr + 32][lk] = a1;
        float4 w0 = *(const float4*)&W[(size_t)(n0 + lr) * D_ + k0 + lk];
        float4 w1 = *(const float4*)&W[(size_t)(n0 + lr + 32) * D_ + k0 + lk];
        *(float4*)&Ws[lr][lk] = w0;
        *(float4*)&Ws[lr + 32][lk] = w1;
      }
      __syncthreads();
      #pragma unroll
      for (int kk = 0; kk < 32; kk += 4) {
        float4 av[4], wv[4];
        #pragma unroll
        for (int i = 0; i < 4; ++i) av[i] = *(const float4*)&As[ty * 4 + i][kk];
        #pragma unroll
        for (int j = 0; j < 4; ++j) wv[j] = *(const float4*)&Ws[tx + 16 * j][kk];
        #pragma unroll
        for (int i = 0; i < 4; ++i)
          #pragma unroll
          for (int j = 0; j < 4; ++j) {
            acc[i][j] = fma((double)av[i].x, (double)wv[j].x, acc[i][j]);
            acc[i][j] = fma((double)av[i].y, (double)wv[j].y, acc[i][j]);
            acc[i][j] = fma((double)av[i].z, (double)wv[j].z, acc[i][j]);
            acc[i][j] = fma((double)av[i].w, (double)wv[j].w, acc[i][j]);
          }
      }
    }
    #pragma unroll
    for (int i = 0; i < 4; ++i) {
      const int m = m0 + ty * 4 + i;
      #pragma unroll
      for (int j = 0; j < 4; ++j) {
        const int n = n0 + tx + 16 * j;
        const double v = acc[i][j] + (double)bias[n];
        qp64[(size_t)m * D_ + n] = v;
        qpb[(size_t)m * D_ + n] = __float2bfloat16((float)v);
      }
    }
    return;
  }

  // ---- cvt + norm (fragment-major candb layout) ----
  const float* src;
  int e4, log2rpb, row_base;
  if (blk < 256 + 4096) { src = ctx; e4 = (blk - 256) * 256 + tid; log2rpb = 12; row_base = 0; }
  else                  { src = mem; e4 = (blk - 4352) * 256 + tid; log2rpb = 6; row_base = C_; }
  const int row = e4 >> 6;
  const int b = row >> log2rpb;
  const int r = row & ((1 << log2rpb) - 1);
  const int k4 = e4 & 63;
  const float4 v = ((const float4*)src)[e4];
  const int R = row_base + r;
  const int g = R >> 4, l15 = R & 15;
  const int k = k4 * 4;
  const int s = k >> 5, lg = (k & 31) >> 3, ii = k & 7;
  unsigned short* d = candb + (size_t)b * (NC * D_) +
                      (size_t)g * 4096 + s * 512 + lg * 128 + l15 * 8 + ii;
  ushort4 o;
  __hip_bfloat16 h0 = __float2bfloat16(v.x); o.x = *(unsigned short*)&h0;
  __hip_bfloat16 h1 = __float2bfloat16(v.y); o.y = *(unsigned short*)&h1;
  __hip_bfloat16 h2 = __float2bfloat16(v.z); o.z = *(unsigned short*)&h2;
  __hip_bfloat16 h3 = __float2bfloat16(v.w); o.w = *(unsigned short*)&h3;
  *(ushort4*)d = o;
  float sacc = v.x * v.x + v.y * v.y + v.z * v.z + v.w * v.w;
  #pragma unroll
  for (int off = 32; off > 0; off >>= 1) sacc += __shfl_down(sacc, off);
  if ((tid & 63) == 0) cn[b * NC + row_base + r] = sacc;
}

// ---------------- pass 1: MFMA + branchless sort4 + order-statistic merge into 8-list ----------------
#define INSERT_CANDS(ACC, CBASE)                                              \
  {                                                                           \
    const float4 cn4 = *(const float4*)&cnb[(CBASE) + lg * 4];                \
    unsigned k0, k1, k2, k3;                                                  \
    {                                                                         \
      unsigned kk[4];                                                         \
      _Pragma("unroll")                                                       \
      for (int r = 0; r < 4; ++r) {                                           \
        const float d2v = fmaf(-2.0f, (ACC)[r], ((const float*)&cn4)[r]);     \
        kk[r] = (__float_as_uint(d2v) & 0xFFFFE000u)                          \
                | (unsigned)((CBASE) + lg * 4 + r);                           \
      }                                                                       \
      unsigned t;                                                             \
      t = UMIN(kk[0], kk[1]); kk[1] = UMAX(kk[0], kk[1]); kk[0] = t;          \
      t = UMIN(kk[2], kk[3]); kk[3] = UMAX(kk[2], kk[3]); kk[2] = t;          \
      t = UMIN(kk[0], kk[2]); kk[2] = UMAX(kk[0], kk[2]); kk[0] = t;          \
      t = UMIN(kk[1], kk[3]); kk[3] = UMAX(kk[1], kk[3]); kk[1] = t;          \
      t = UMIN(kk[1], kk[2]); kk[2] = UMAX(kk[1], kk[2]); kk[1] = t;          \
      k0 = kk[0]; k1 = kk[1]; k2 = kk[2]; k3 = kk[3];                         \
    }                                                                         \
    unsigned nl[LTOP];                                                        \
    nl[0] = UMIN(ld[0], k0);                                                  \
    nl[1] = UMIN(UMIN(ld[1], UMAX(ld[0], k0)), k1);                           \
    nl[2] = UMIN(UMIN(ld[2], UMAX(ld[1], k0)),                                \
                 UMIN(UMAX(ld[0], k1), k2));                                  \
    nl[3] = UMIN(UMIN(UMIN(ld[3], UMAX(ld[2], k0)),                           \
                      UMIN(UMAX(ld[1], k1), UMAX(ld[0], k2))), k3);           \
    _Pragma("unroll")                                                         \
    for (int i = 4; i < LTOP; ++i) {                                          \
      nl[i] = UMIN(UMIN(UMIN(ld[i], UMAX(ld[i - 1], k0)),                     \
                        UMIN(UMAX(ld[i - 2], k1), UMAX(ld[i - 3], k2))),      \
                   UMAX(ld[i - 4], k3));                                      \
    }                                                                         \
    _Pragma("unroll")                                                         \
    for (int i = 0; i < LTOP; ++i) ld[i] = nl[i];                             \
  }

#define MFMA_CHAIN(ACC, FRAGS)                                                \
  f32x4 ACC;                                                                  \
  {                                                                           \
    f32x4 c0_ = {0.f,0.f,0.f,0.f}, c1_ = {0.f,0.f,0.f,0.f};                   \
    f32x4 c2_ = {0.f,0.f,0.f,0.f}, c3_ = {0.f,0.f,0.f,0.f};                   \
    c0_ = __builtin_amdgcn_mfma_f32_16x16x32_bf16((FRAGS)[0], bfr[0], c0_, 0, 0, 0); \
    c1_ = __builtin_amdgcn_mfma_f32_16x16x32_bf16((FRAGS)[1], bfr[1], c1_, 0, 0, 0); \
    c2_ = __builtin_amdgcn_mfma_f32_16x16x32_bf16((FRAGS)[2], bfr[2], c2_, 0, 0, 0); \
    c3_ = __builtin_amdgcn_mfma_f32_16x16x32_bf16((FRAGS)[3], bfr[3], c3_, 0, 0, 0); \
    c0_ = __builtin_amdgcn_mfma_f32_16x16x32_bf16((FRAGS)[4], bfr[4], c0_, 0, 0, 0); \
    c1_ = __builtin_amdgcn_mfma_f32_16x16x32_bf16((FRAGS)[5], bfr[5], c1_, 0, 0, 0); \
    c2_ = __builtin_amdgcn_mfma_f32_16x16x32_bf16((FRAGS)[6], bfr[6], c2_, 0, 0, 0); \
    c3_ = __builtin_amdgcn_mfma_f32_16x16x32_bf16((FRAGS)[7], bfr[7], c3_, 0, 0, 0); \
    ACC = (c0_ + c1_) + (c2_ + c3_);                                          \
  }

// grid 2048 = 4 batch x 8 split x 64 row-tiles. Per wave: 8 groups (4 j x 2).
// __launch_bounds__(256, 4): min 4 waves/SIMD -> VGPR cap 128, prevents the
// R13 allocator cliff (VGPR 184, occupancy 10.5%).
__global__ __launch_bounds__(256, 4) void dist_topk_kernel(
    const __hip_bfloat16* __restrict__ qpb, const unsigned short* __restrict__ candb,
    const float* __restrict__ cn, unsigned* __restrict__ topidx)
{
  const int b = blockIdx.x & 3;
  const int split = (blockIdx.x >> 2) & 7;
  const int rt = blockIdx.x >> 5;          // 0..63
  const int row0 = rt * 16;
  const int tid = threadIdx.x;
  const int w = tid >> 6;          // wave 0..3
  const int lane = tid & 63;
  const int l15 = lane & 15;
  const int lg = lane >> 4;        // 0..3

  __shared__ unsigned md[16][16][LTOP + 1];   // [row][list][entry], pad 9

  short8 bfr[8];
  {
    const short* qrow = (const short*)qpb + ((size_t)(b * S_ + row0 + l15)) * D_ + lg * 8;
    #pragma unroll
    for (int s = 0; s < 8; ++s) bfr[s] = *(const short8*)(qrow + s * 32);
  }

  const float* cnb = cn + b * NC;
  const short* cbp = (const short*)candb + (size_t)b * NC * D_ + lg * 128 + l15 * 8;

  unsigned ld[LTOP];
  #pragma unroll
  for (int i = 0; i < LTOP; ++i) ld[i] = 0xFFFFFFFFu;

  const bool has_tail = (w == 3 && split < 4);
  const int gtail = 256 + split;

  short8 aA[8], aB[8];
  #pragma unroll
  for (int s = 0; s < 8; ++s)
    aA[s] = *(const short8*)(cbp + (size_t)(split + 8 * w) * 4096 + s * 512);

  for (int j = 0; j < 4; ++j) {
    const int gA = split + 8 * (w + 8 * j);
    const int gB = gA + 32;
    #pragma unroll
    for (int s = 0; s < 8; ++s)
      aB[s] = *(const short8*)(cbp + (size_t)gB * 4096 + s * 512);

    MFMA_CHAIN(acc, aA);

    if (j < 3) {
      #pragma unroll
      for (int s = 0; s < 8; ++s)
        aA[s] = *(const short8*)(cbp + (size_t)(gA + 64) * 4096 + s * 512);
    } else if (has_tail) {
      #pragma unroll
      for (int s = 0; s < 8; ++s)
        aA[s] = *(const short8*)(cbp + (size_t)gtail * 4096 + s * 512);
    }

    MFMA_CHAIN(acc2, aB);

    INSERT_CANDS(acc, gA * 16);
    INSERT_CANDS(acc2, gB * 16);
  }
  if (has_tail) {   // memory-candidate group
    MFMA_CHAIN(acc, aA);
    INSERT_CANDS(acc, gtail * 16);
  }

  const int lid = w * 4 + lg;
  #pragma unroll
  for (int i = 0; i < LTOP; ++i) md[l15][lid][i] = ld[i];
  __syncthreads();

  // 16-way head-pointer merge of 8-deep lists -> per-(row,split) top-16
  {
    const int g = lane >> 4;          // row-in-wave 0..3
    const int h = l15;                // list id
    const int row = w * 4 + g;
    int ptr = 0;
    unsigned cur = md[row][h][0];
    unsigned mykey = 0xFFFFFFFFu;     // lane h captures the h-th smallest
    #pragma unroll
    for (int it = 0; it < TOPN; ++it) {
      unsigned m = cur;
      #pragma unroll
      for (int off = 8; off > 0; off >>= 1) {
        const unsigned o = __shfl_xor(m, off, 16);
        m = (o < m) ? o : m;
      }
      if (h == it) mykey = m;
      if (cur == m) {                 // unique winner advances its head
        ++ptr;
        cur = (ptr < LTOP) ? md[row][h][ptr] : 0xFFFFFFFFu;
      }
    }
    unsigned* dst = topidx + ((size_t)(b * S_ + row0 + row)) * CANDK + split * TOPN;
    dst[h] = mykey;
  }
}

// ---------------- pass 2: dual key-presort -> select 32 -> fp64 refine -> bitonic top-16 ----------------
__global__ __launch_bounds__(256) void refine_kernel(
    const double* __restrict__ qp64, const float* __restrict__ ctx,
    const float* __restrict__ mem, const unsigned* __restrict__ topidx,
    float* __restrict__ out)
{
  const int row_global = blockIdx.x;
  const int tid = threadIdx.x;
  const int w = tid >> 6;         // wave 0..3: candidates [w*8, w*8+8)
  const int lane = tid & 63;
  const int c2 = lane >> 5;       // which cand of the pair
  const int ll = lane & 31;       // dim slice: [ll*8, ll*8+8)
  const int b = row_global >> 10;

  __shared__ unsigned sA[64], sB[64];
  __shared__ double d2s[64];
  __shared__ int    ids_s[64];

  // waves 0 and 1: bitonic-sort the two 64-key halves (ascending)
  if (w < 2) {
    unsigned key = topidx[(size_t)row_global * CANDK + w * 64 + lane];
    #pragma unroll
    for (int k = 2; k <= 64; k <<= 1) {
      #pragma unroll
      for (int j2 = k >> 1; j2 > 0; j2 >>= 1) {
        const unsigned o = __shfl_xor(key, j2);
        const bool up = ((lane & k) == 0);
        const bool keep_min = (((lane & j2) == 0) == up);
        const bool less = key < o;
        if (keep_min ? !less : less) key = o;
      }
    }
    if (w == 0) sA[lane] = key; else sB[lane] = key;
  }
  if (w == 2 && lane < 32) { d2s[32 + lane] = DBL_MAX; ids_s[32 + lane] = 0x7fffffff; }
  __syncthreads();

  const double* qrow = qp64 + (size_t)row_global * D_;
  double qd[8];
  #pragma unroll
  for (int t = 0; t < 8; t += 2) {
    double2 v = *(const double2*)&qrow[ll * 8 + t];
    qd[t] = v.x; qd[t + 1] = v.y;
  }

  // smallest-32 of two sorted-64s: sel(p) = min(sA[p], sB[31-p]), p = 0..31
  int cis[4]; float4 cva[4], cvb[4];
  #pragma unroll
  for (int j = 0; j < 4; ++j) {
    const int p = w * 8 + 2 * j + c2;
    const unsigned kk = UMIN(sA[p], sB[31 - p]);
    cis[j] = (int)(kk & 0x1FFFu);
  }
  #pragma unroll
  for (int j = 0; j < 4; ++j) {
    const int ci = cis[j];
    const float* cp = (ci < C_) ? ctx + ((size_t)b * C_ + ci) * D_
                                : mem + ((size_t)b * K_ + (ci - C_)) * D_;
    cva[j] = *(const float4*)&cp[ll * 8];
    cvb[j] = *(const float4*)&cp[ll * 8 + 4];
  }

  #pragma unroll
  for (int j = 0; j < 4; ++j) {
    double a0 = 0.0, a1 = 0.0, df;
    df = qd[0] - (double)cva[j].x; a0 = fma(df, df, a0);
    df = qd[1] - (double)cva[j].y; a1 = fma(df, df, a1);
    df = qd[2] - (double)cva[j].z; a0 = fma(df, df, a0);
    df = qd[3] - (double)cva[j].w; a1 = fma(df, df, a1);
    df = qd[4] - (double)cvb[j].x; a0 = fma(df, df, a0);
    df = qd[5] - (double)cvb[j].y; a1 = fma(df, df, a1);
    df = qd[6] - (double)cvb[j].z; a0 = fma(df, df, a0);
    df = qd[7] - (double)cvb[j].w; a1 = fma(df, df, a1);
    double acc = a0 + a1;
    #pragma unroll
    for (int off = 16; off > 0; off >>= 1) acc += __shfl_down(acc, off, 32);
    if (ll == 0) { d2s[w * 8 + 2 * j + c2] = acc; ids_s[w * 8 + 2 * j + c2] = cis[j]; }
  }
  __syncthreads();

  // wave 0: exact bitonic sort of 32 real + 32 pad (d2, idx) pairs
  if (w == 0) {
    double d2 = d2s[lane];
    int    ci = ids_s[lane];
    #pragma unroll
    for (int k = 2; k <= 64; k <<= 1) {
      #pragma unroll
      for (int j2 = k >> 1; j2 > 0; j2 >>= 1) {
        const double od2 = __shfl_xor(d2, j2);
        const int    oci = __shfl_xor(ci, j2);
        const bool up = ((lane & k) == 0);
        const bool less = (d2 < od2) || (d2 == od2 && ci < oci);
        const bool keep_min = (((lane & j2) == 0) == up);
        const bool take = keep_min ? !less : less;
        if (take) { d2 = od2; ci = oci; }
      }
    }
    if (lane < TOPN) {
      const size_t obase = (size_t)row_global * TOPN;
      out[obase + lane] = (float)sqrt(d2 < 0.0 ? 0.0 : d2);
      out[(size_t)B_ * S_ * TOPN + obase + lane] = (float)ci;
    }
  }
}

extern "C" void kernel_launch(void* const* d_in, const int* in_sizes, int n_in,
                              void* d_out, int out_size, void* d_ws, size_t ws_size,
                              hipStream_t stream) {
  const float* q    = (const float*)d_in[0];
  const float* ctx  = (const float*)d_in[1];
  const float* mem  = (const float*)d_in[2];
  const float* W    = (const float*)d_in[3];
  const float* bias = (const float*)d_in[4];
  float* out = (float*)d_out;

  double* qp64 = (double*)d_ws;                                             // 8 MB
  __hip_bfloat16* qpb = (__hip_bfloat16*)(qp64 + (size_t)B_ * S_ * D_);     // 2 MB
  unsigned short* candb = (unsigned short*)(qpb + (size_t)B_ * S_ * D_);    // 8.5 MB
  float* cn    = (float*)(candb + (size_t)B_ * NC * D_);                    // 66.5 KB
  unsigned* topidx = (unsigned*)(cn + (size_t)B_ * NC);                     // 2 MB

  prep_kernel<<<4416, 256, 0, stream>>>(q, W, bias, qp64, qpb, ctx, mem, candb, cn);
  dist_topk_kernel<<<2048, 256, 0, stream>>>(qpb, candb, cn, topidx);
  refine_kernel<<<B_ * S_, 256, 0, stream>>>(qp64, ctx, mem, topidx, out);
}

// Round 15
// 86.725 us; speedup vs baseline: 1.7518x; 1.7518x over previous
//
#include <hip/hip_runtime.h>
#include <hip/hip_bf16.h>
#include <cfloat>
#include <cmath>

#define B_ 4
#define S_ 1024
#define C_ 4096
#define K_ 64
#define D_ 256
#define NC 4160   // C_ + K_  (= 260 groups of 16)
#define TOPN 16
#define NSPLIT 8
#define CANDK 128 // 8 splits x 16 keys; refine narrows to 32 by key

typedef __attribute__((ext_vector_type(8))) short short8;
typedef __attribute__((ext_vector_type(4))) float f32x4;

#define UMIN(a, b) ((a) < (b) ? (a) : (b))
#define UMAX(a, b) ((a) < (b) ? (b) : (a))

// ---------------- fused prep ----------------
// blocks 0..511:    projection, 32x64 tiles (2 blocks/CU -> better tail balance)
// blocks 512..4607: cvt/norm ctx
// blocks 4608..4671: cvt/norm mem
__global__ __launch_bounds__(256) void prep_kernel(
    const float* __restrict__ q, const float* __restrict__ W,
    const float* __restrict__ bias, double* __restrict__ qp64,
    __hip_bfloat16* __restrict__ qpb,
    const float* __restrict__ ctx, const float* __restrict__ mem,
    unsigned short* __restrict__ candb, float* __restrict__ cn)
{
  __shared__ alignas(16) float As[32][36];
  __shared__ alignas(16) float Ws[64][36];
  const int blk = blockIdx.x;
  const int tid = threadIdx.x;

  if (blk < 512) {   // ---- projection: 32 rows x 64 cols per block ----
    const int m0 = (blk >> 2) * 32;      // 128 row-tiles
    const int n0 = (blk & 3) * 64;       // 4 col-tiles
    const int tx = tid & 15;
    const int ty = tid >> 4;             // 0..15 -> rows ty*2 + i
    const int lr = tid >> 3;             // 0..31
    const int lk = (tid & 7) * 4;
    double acc[2][4] = {};
    for (int k0 = 0; k0 < D_; k0 += 32) {
      __syncthreads();
      {
        float4 a0 = *(const float4*)&q[(size_t)(m0 + lr) * D_ + k0 + lk];
        *(float4*)&As[lr][lk] = a0;
        float4 w0 = *(const float4*)&W[(size_t)(n0 + lr) * D_ + k0 + lk];
        float4 w1 = *(const float4*)&W[(size_t)(n0 + lr + 32) * D_ + k0 + lk];
        *(float4*)&Ws[lr][lk] = w0;
        *(float4*)&Ws[lr + 32][lk] = w1;
      }
      __syncthreads();
      #pragma unroll
      for (int kk = 0; kk < 32; kk += 4) {
        float4 av[2], wv[4];
        #pragma unroll
        for (int i = 0; i < 2; ++i) av[i] = *(const float4*)&As[ty * 2 + i][kk];
        #pragma unroll
        for (int j = 0; j < 4; ++j) wv[j] = *(const float4*)&Ws[tx + 16 * j][kk];
        #pragma unroll
        for (int i = 0; i < 2; ++i)
          #pragma unroll
          for (int j = 0; j < 4; ++j) {
            acc[i][j] = fma((double)av[i].x, (double)wv[j].x, acc[i][j]);
            acc[i][j] = fma((double)av[i].y, (double)wv[j].y, acc[i][j]);
            acc[i][j] = fma((double)av[i].z, (double)wv[j].z, acc[i][j]);
            acc[i][j] = fma((double)av[i].w, (double)wv[j].w, acc[i][j]);
          }
      }
    }
    #pragma unroll
    for (int i = 0; i < 2; ++i) {
      const int m = m0 + ty * 2 + i;
      #pragma unroll
      for (int j = 0; j < 4; ++j) {
        const int n = n0 + tx + 16 * j;
        const double v = acc[i][j] + (double)bias[n];
        qp64[(size_t)m * D_ + n] = v;
        qpb[(size_t)m * D_ + n] = __float2bfloat16((float)v);
      }
    }
    return;
  }

  // ---- cvt + norm (fragment-major candb layout) ----
  const float* src;
  int e4, log2rpb, row_base;
  if (blk < 512 + 4096) { src = ctx; e4 = (blk - 512) * 256 + tid; log2rpb = 12; row_base = 0; }
  else                  { src = mem; e4 = (blk - 4608) * 256 + tid; log2rpb = 6; row_base = C_; }
  const int row = e4 >> 6;
  const int b = row >> log2rpb;
  const int r = row & ((1 << log2rpb) - 1);
  const int k4 = e4 & 63;
  const float4 v = ((const float4*)src)[e4];
  const int R = row_base + r;
  const int g = R >> 4, l15 = R & 15;
  const int k = k4 * 4;
  const int s = k >> 5, lg = (k & 31) >> 3, ii = k & 7;
  unsigned short* d = candb + (size_t)b * (NC * D_) +
                      (size_t)g * 4096 + s * 512 + lg * 128 + l15 * 8 + ii;
  ushort4 o;
  __hip_bfloat16 h0 = __float2bfloat16(v.x); o.x = *(unsigned short*)&h0;
  __hip_bfloat16 h1 = __float2bfloat16(v.y); o.y = *(unsigned short*)&h1;
  __hip_bfloat16 h2 = __float2bfloat16(v.z); o.z = *(unsigned short*)&h2;
  __hip_bfloat16 h3 = __float2bfloat16(v.w); o.w = *(unsigned short*)&h3;
  *(ushort4*)d = o;
  float sacc = v.x * v.x + v.y * v.y + v.z * v.z + v.w * v.w;
  #pragma unroll
  for (int off = 32; off > 0; off >>= 1) sacc += __shfl_down(sacc, off);
  if ((tid & 63) == 0) cn[b * NC + row_base + r] = sacc;
}

// ---------------- pass 1 (byte-exact R12): MFMA + sort4 + order-stat merge, LTOP=16 ----------------
#define INSERT_CANDS(ACC, CBASE)                                              \
  {                                                                           \
    const float4 cn4 = *(const float4*)&cnb[(CBASE) + lg * 4];                \
    unsigned k0, k1, k2, k3;                                                  \
    {                                                                         \
      unsigned kk[4];                                                         \
      _Pragma("unroll")                                                       \
      for (int r = 0; r < 4; ++r) {                                           \
        const float d2v = fmaf(-2.0f, (ACC)[r], ((const float*)&cn4)[r]);     \
        kk[r] = (__float_as_uint(d2v) & 0xFFFFE000u)                          \
                | (unsigned)((CBASE) + lg * 4 + r);                           \
      }                                                                       \
      unsigned t;                                                             \
      t = UMIN(kk[0], kk[1]); kk[1] = UMAX(kk[0], kk[1]); kk[0] = t;          \
      t = UMIN(kk[2], kk[3]); kk[3] = UMAX(kk[2], kk[3]); kk[2] = t;          \
      t = UMIN(kk[0], kk[2]); kk[2] = UMAX(kk[0], kk[2]); kk[0] = t;          \
      t = UMIN(kk[1], kk[3]); kk[3] = UMAX(kk[1], kk[3]); kk[1] = t;          \
      t = UMIN(kk[1], kk[2]); kk[2] = UMAX(kk[1], kk[2]); kk[1] = t;          \
      k0 = kk[0]; k1 = kk[1]; k2 = kk[2]; k3 = kk[3];                         \
    }                                                                         \
    unsigned nl[16];                                                          \
    nl[0] = UMIN(ld[0], k0);                                                  \
    nl[1] = UMIN(UMIN(ld[1], UMAX(ld[0], k0)), k1);                           \
    nl[2] = UMIN(UMIN(ld[2], UMAX(ld[1], k0)),                                \
                 UMIN(UMAX(ld[0], k1), k2));                                  \
    nl[3] = UMIN(UMIN(UMIN(ld[3], UMAX(ld[2], k0)),                           \
                      UMIN(UMAX(ld[1], k1), UMAX(ld[0], k2))), k3);           \
    _Pragma("unroll")                                                         \
    for (int i = 4; i < 16; ++i) {                                            \
      nl[i] = UMIN(UMIN(UMIN(ld[i], UMAX(ld[i - 1], k0)),                     \
                        UMIN(UMAX(ld[i - 2], k1), UMAX(ld[i - 3], k2))),      \
                   UMAX(ld[i - 4], k3));                                      \
    }                                                                         \
    _Pragma("unroll")                                                         \
    for (int i = 0; i < 16; ++i) ld[i] = nl[i];                               \
  }

#define MFMA_CHAIN(ACC, FRAGS)                                                \
  f32x4 ACC;                                                                  \
  {                                                                           \
    f32x4 c0_ = {0.f,0.f,0.f,0.f}, c1_ = {0.f,0.f,0.f,0.f};                   \
    f32x4 c2_ = {0.f,0.f,0.f,0.f}, c3_ = {0.f,0.f,0.f,0.f};                   \
    c0_ = __builtin_amdgcn_mfma_f32_16x16x32_bf16((FRAGS)[0], bfr[0], c0_, 0, 0, 0); \
    c1_ = __builtin_amdgcn_mfma_f32_16x16x32_bf16((FRAGS)[1], bfr[1], c1_, 0, 0, 0); \
    c2_ = __builtin_amdgcn_mfma_f32_16x16x32_bf16((FRAGS)[2], bfr[2], c2_, 0, 0, 0); \
    c3_ = __builtin_amdgcn_mfma_f32_16x16x32_bf16((FRAGS)[3], bfr[3], c3_, 0, 0, 0); \
    c0_ = __builtin_amdgcn_mfma_f32_16x16x32_bf16((FRAGS)[4], bfr[4], c0_, 0, 0, 0); \
    c1_ = __builtin_amdgcn_mfma_f32_16x16x32_bf16((FRAGS)[5], bfr[5], c1_, 0, 0, 0); \
    c2_ = __builtin_amdgcn_mfma_f32_16x16x32_bf16((FRAGS)[6], bfr[6], c2_, 0, 0, 0); \
    c3_ = __builtin_amdgcn_mfma_f32_16x16x32_bf16((FRAGS)[7], bfr[7], c3_, 0, 0, 0); \
    ACC = (c0_ + c1_) + (c2_ + c3_);                                          \
  }

// grid 2048 = 4 batch x 8 split x 64 row-tiles. Per wave: 8 groups (4 j x 2).
__global__ __launch_bounds__(256) void dist_topk_kernel(
    const __hip_bfloat16* __restrict__ qpb, const unsigned short* __restrict__ candb,
    const float* __restrict__ cn, unsigned* __restrict__ topidx)
{
  const int b = blockIdx.x & 3;
  const int split = (blockIdx.x >> 2) & 7;
  const int rt = blockIdx.x >> 5;          // 0..63
  const int row0 = rt * 16;
  const int tid = threadIdx.x;
  const int w = tid >> 6;          // wave 0..3
  const int lane = tid & 63;
  const int l15 = lane & 15;
  const int lg = lane >> 4;        // 0..3

  __shared__ unsigned md[16][16][17];   // [row][list][entry], pad 17

  short8 bfr[8];
  {
    const short* qrow = (const short*)qpb + ((size_t)(b * S_ + row0 + l15)) * D_ + lg * 8;
    #pragma unroll
    for (int s = 0; s < 8; ++s) bfr[s] = *(const short8*)(qrow + s * 32);
  }

  const float* cnb = cn + b * NC;
  const short* cbp = (const short*)candb + (size_t)b * NC * D_ + lg * 128 + l15 * 8;

  unsigned ld[16];
  #pragma unroll
  for (int i = 0; i < TOPN; ++i) ld[i] = 0xFFFFFFFFu;

  const bool has_tail = (w == 3 && split < 4);
  const int gtail = 256 + split;

  short8 aA[8], aB[8];
  #pragma unroll
  for (int s = 0; s < 8; ++s)
    aA[s] = *(const short8*)(cbp + (size_t)(split + 8 * w) * 4096 + s * 512);

  for (int j = 0; j < 4; ++j) {
    const int gA = split + 8 * (w + 8 * j);
    const int gB = gA + 32;
    #pragma unroll
    for (int s = 0; s < 8; ++s)
      aB[s] = *(const short8*)(cbp + (size_t)gB * 4096 + s * 512);

    MFMA_CHAIN(acc, aA);

    if (j < 3) {
      #pragma unroll
      for (int s = 0; s < 8; ++s)
        aA[s] = *(const short8*)(cbp + (size_t)(gA + 64) * 4096 + s * 512);
    } else if (has_tail) {
      #pragma unroll
      for (int s = 0; s < 8; ++s)
        aA[s] = *(const short8*)(cbp + (size_t)gtail * 4096 + s * 512);
    }

    MFMA_CHAIN(acc2, aB);

    INSERT_CANDS(acc, gA * 16);
    INSERT_CANDS(acc2, gB * 16);
  }
  if (has_tail) {   // memory-candidate group
    MFMA_CHAIN(acc, aA);
    INSERT_CANDS(acc, gtail * 16);
  }

  const int lid = w * 4 + lg;
  #pragma unroll
  for (int i = 0; i < TOPN; ++i) md[l15][lid][i] = ld[i];
  __syncthreads();

  {
    const int g = lane >> 4;          // row-in-wave 0..3
    const int h = l15;                // list id
    const int row = w * 4 + g;
    int ptr = 0;
    unsigned cur = md[row][h][0];
    unsigned mykey = 0xFFFFFFFFu;     // lane h captures the h-th smallest
    #pragma unroll
    for (int it = 0; it < TOPN; ++it) {
      unsigned m = cur;
      #pragma unroll
      for (int off = 8; off > 0; off >>= 1) {
        const unsigned o = __shfl_xor(m, off, 16);
        m = (o < m) ? o : m;
      }
      if (h == it) mykey = m;
      if (cur == m) {                 // unique winner advances its head
        ++ptr;
        cur = (ptr < TOPN) ? md[row][h][ptr] : 0xFFFFFFFFu;
      }
    }
    unsigned* dst = topidx + ((size_t)(b * S_ + row0 + row)) * CANDK + split * TOPN;
    dst[h] = mykey;
  }
}

// ---------------- pass 2: dual key-presort -> select 32 -> fp64 refine -> bitonic top-16 ----------------
__global__ __launch_bounds__(256) void refine_kernel(
    const double* __restrict__ qp64, const float* __restrict__ ctx,
    const float* __restrict__ mem, const unsigned* __restrict__ topidx,
    float* __restrict__ out)
{
  const int row_global = blockIdx.x;
  const int tid = threadIdx.x;
  const int w = tid >> 6;         // wave 0..3: candidates [w*8, w*8+8)
  const int lane = tid & 63;
  const int c2 = lane >> 5;       // which cand of the pair
  const int ll = lane & 31;       // dim slice: [ll*8, ll*8+8)
  const int b = row_global >> 10;

  __shared__ unsigned sA[64], sB[64];
  __shared__ double d2s[64];
  __shared__ int    ids_s[64];

  // waves 0 and 1: bitonic-sort the two 64-key halves (ascending)
  if (w < 2) {
    unsigned key = topidx[(size_t)row_global * CANDK + w * 64 + lane];
    #pragma unroll
    for (int k = 2; k <= 64; k <<= 1) {
      #pragma unroll
      for (int j2 = k >> 1; j2 > 0; j2 >>= 1) {
        const unsigned o = __shfl_xor(key, j2);
        const bool up = ((lane & k) == 0);
        const bool keep_min = (((lane & j2) == 0) == up);
        const bool less = key < o;
        if (keep_min ? !less : less) key = o;
      }
    }
    if (w == 0) sA[lane] = key; else sB[lane] = key;
  }
  if (w == 2 && lane < 32) { d2s[32 + lane] = DBL_MAX; ids_s[32 + lane] = 0x7fffffff; }
  __syncthreads();

  const double* qrow = qp64 + (size_t)row_global * D_;
  double qd[8];
  #pragma unroll
  for (int t = 0; t < 8; t += 2) {
    double2 v = *(const double2*)&qrow[ll * 8 + t];
    qd[t] = v.x; qd[t + 1] = v.y;
  }

  // smallest-32 of two sorted-64s: sel(p) = min(sA[p], sB[31-p]), p = 0..31
  int cis[4]; float4 cva[4], cvb[4];
  #pragma unroll
  for (int j = 0; j < 4; ++j) {
    const int p = w * 8 + 2 * j + c2;
    const unsigned kk = UMIN(sA[p], sB[31 - p]);
    cis[j] = (int)(kk & 0x1FFFu);
  }
  #pragma unroll
  for (int j = 0; j < 4; ++j) {
    const int ci = cis[j];
    const float* cp = (ci < C_) ? ctx + ((size_t)b * C_ + ci) * D_
                                : mem + ((size_t)b * K_ + (ci - C_)) * D_;
    cva[j] = *(const float4*)&cp[ll * 8];
    cvb[j] = *(const float4*)&cp[ll * 8 + 4];
  }

  #pragma unroll
  for (int j = 0; j < 4; ++j) {
    double a0 = 0.0, a1 = 0.0, df;
    df = qd[0] - (double)cva[j].x; a0 = fma(df, df, a0);
    df = qd[1] - (double)cva[j].y; a1 = fma(df, df, a1);
    df = qd[2] - (double)cva[j].z; a0 = fma(df, df, a0);
    df = qd[3] - (double)cva[j].w; a1 = fma(df, df, a1);
    df = qd[4] - (double)cvb[j].x; a0 = fma(df, df, a0);
    df = qd[5] - (double)cvb[j].y; a1 = fma(df, df, a1);
    df = qd[6] - (double)cvb[j].z; a0 = fma(df, df, a0);
    df = qd[7] - (double)cvb[j].w; a1 = fma(df, df, a1);
    double acc = a0 + a1;
    #pragma unroll
    for (int off = 16; off > 0; off >>= 1) acc += __shfl_down(acc, off, 32);
    if (ll == 0) { d2s[w * 8 + 2 * j + c2] = acc; ids_s[w * 8 + 2 * j + c2] = cis[j]; }
  }
  __syncthreads();

  // wave 0: exact bitonic sort of 32 real + 32 pad (d2, idx) pairs
  if (w == 0) {
    double d2 = d2s[lane];
    int    ci = ids_s[lane];
    #pragma unroll
    for (int k = 2; k <= 64; k <<= 1) {
      #pragma unroll
      for (int j2 = k >> 1; j2 > 0; j2 >>= 1) {
        const double od2 = __shfl_xor(d2, j2);
        const int    oci = __shfl_xor(ci, j2);
        const bool up = ((lane & k) == 0);
        const bool less = (d2 < od2) || (d2 == od2 && ci < oci);
        const bool keep_min = (((lane & j2) == 0) == up);
        const bool take = keep_min ? !less : less;
        if (take) { d2 = od2; ci = oci; }
      }
    }
    if (lane < TOPN) {
      const size_t obase = (size_t)row_global * TOPN;
      out[obase + lane] = (float)sqrt(d2 < 0.0 ? 0.0 : d2);
      out[(size_t)B_ * S_ * TOPN + obase + lane] = (float)ci;
    }
  }
}

extern "C" void kernel_launch(void* const* d_in, const int* in_sizes, int n_in,
                              void* d_out, int out_size, void* d_ws, size_t ws_size,
                              hipStream_t stream) {
  const float* q    = (const float*)d_in[0];
  const float* ctx  = (const float*)d_in[1];
  const float* mem  = (const float*)d_in[2];
  const float* W    = (const float*)d_in[3];
  const float* bias = (const float*)d_in[4];
  float* out = (float*)d_out;

  double* qp64 = (double*)d_ws;                                             // 8 MB
  __hip_bfloat16* qpb = (__hip_bfloat16*)(qp64 + (size_t)B_ * S_ * D_);     // 2 MB
  unsigned short* candb = (unsigned short*)(qpb + (size_t)B_ * S_ * D_);    // 8.5 MB
  float* cn    = (float*)(candb + (size_t)B_ * NC * D_);                    // 66.5 KB
  unsigned* topidx = (unsigned*)(cn + (size_t)B_ * NC);                     // 2 MB

  prep_kernel<<<4672, 256, 0, stream>>>(q, W, bias, qp64, qpb, ctx, mem, candb, cn);
  dist_topk_kernel<<<2048, 256, 0, stream>>>(qpb, candb, cn, topidx);
  refine_kernel<<<B_ * S_, 256, 0, stream>>>(qp64, ctx, mem, topidx, out);
}

// Round 17
// 78.549 us; speedup vs baseline: 1.9341x; 1.1041x over previous
//
#include <hip/hip_runtime.h>
#include <hip/hip_bf16.h>
#include <cfloat>
#include <cmath>

#define B_ 4
#define S_ 1024
#define C_ 4096
#define K_ 64
#define D_ 256
#define NC 4160   // C_ + K_  (= 260 groups of 16)
#define TOPN 16
#define NSPLIT 8
#define CANDK 128 // 8 splits x 16 keys; refine narrows to 32 by key

typedef __attribute__((ext_vector_type(8))) short short8;
typedef __attribute__((ext_vector_type(4))) float f32x4;

#define UMIN(a, b) ((a) < (b) ? (a) : (b))
#define UMAX(a, b) ((a) < (b) ? (b) : (a))

// ---------------- fused prep (unchanged from R15) ----------------
__global__ __launch_bounds__(256) void prep_kernel(
    const float* __restrict__ q, const float* __restrict__ W,
    const float* __restrict__ bias, double* __restrict__ qp64,
    __hip_bfloat16* __restrict__ qpb,
    const float* __restrict__ ctx, const float* __restrict__ mem,
    unsigned short* __restrict__ candb, float* __restrict__ cn)
{
  __shared__ alignas(16) float As[32][36];
  __shared__ alignas(16) float Ws[64][36];
  const int blk = blockIdx.x;
  const int tid = threadIdx.x;

  if (blk < 512) {   // ---- projection: 32 rows x 64 cols per block ----
    const int m0 = (blk >> 2) * 32;
    const int n0 = (blk & 3) * 64;
    const int tx = tid & 15;
    const int ty = tid >> 4;
    const int lr = tid >> 3;
    const int lk = (tid & 7) * 4;
    double acc[2][4] = {};
    for (int k0 = 0; k0 < D_; k0 += 32) {
      __syncthreads();
      {
        float4 a0 = *(const float4*)&q[(size_t)(m0 + lr) * D_ + k0 + lk];
        *(float4*)&As[lr][lk] = a0;
        float4 w0 = *(const float4*)&W[(size_t)(n0 + lr) * D_ + k0 + lk];
        float4 w1 = *(const float4*)&W[(size_t)(n0 + lr + 32) * D_ + k0 + lk];
        *(float4*)&Ws[lr][lk] = w0;
        *(float4*)&Ws[lr + 32][lk] = w1;
      }
      __syncthreads();
      #pragma unroll
      for (int kk = 0; kk < 32; kk += 4) {
        float4 av[2], wv[4];
        #pragma unroll
        for (int i = 0; i < 2; ++i) av[i] = *(const float4*)&As[ty * 2 + i][kk];
        #pragma unroll
        for (int j = 0; j < 4; ++j) wv[j] = *(const float4*)&Ws[tx + 16 * j][kk];
        #pragma unroll
        for (int i = 0; i < 2; ++i)
          #pragma unroll
          for (int j = 0; j < 4; ++j) {
            acc[i][j] = fma((double)av[i].x, (double)wv[j].x, acc[i][j]);
            acc[i][j] = fma((double)av[i].y, (double)wv[j].y, acc[i][j]);
            acc[i][j] = fma((double)av[i].z, (double)wv[j].z, acc[i][j]);
            acc[i][j] = fma((double)av[i].w, (double)wv[j].w, acc[i][j]);
          }
      }
    }
    #pragma unroll
    for (int i = 0; i < 2; ++i) {
      const int m = m0 + ty * 2 + i;
      #pragma unroll
      for (int j = 0; j < 4; ++j) {
        const int n = n0 + tx + 16 * j;
        const double v = acc[i][j] + (double)bias[n];
        qp64[(size_t)m * D_ + n] = v;
        qpb[(size_t)m * D_ + n] = __float2bfloat16((float)v);
      }
    }
    return;
  }

  // ---- cvt + norm (fragment-major candb layout) ----
  const float* src;
  int e4, log2rpb, row_base;
  if (blk < 512 + 4096) { src = ctx; e4 = (blk - 512) * 256 + tid; log2rpb = 12; row_base = 0; }
  else                  { src = mem; e4 = (blk - 4608) * 256 + tid; log2rpb = 6; row_base = C_; }
  const int row = e4 >> 6;
  const int b = row >> log2rpb;
  const int r = row & ((1 << log2rpb) - 1);
  const int k4 = e4 & 63;
  const float4 v = ((const float4*)src)[e4];
  const int R = row_base + r;
  const int g = R >> 4, l15 = R & 15;
  const int k = k4 * 4;
  const int s = k >> 5, lg = (k & 31) >> 3, ii = k & 7;
  unsigned short* d = candb + (size_t)b * (NC * D_) +
                      (size_t)g * 4096 + s * 512 + lg * 128 + l15 * 8 + ii;
  ushort4 o;
  __hip_bfloat16 h0 = __float2bfloat16(v.x); o.x = *(unsigned short*)&h0;
  __hip_bfloat16 h1 = __float2bfloat16(v.y); o.y = *(unsigned short*)&h1;
  __hip_bfloat16 h2 = __float2bfloat16(v.z); o.z = *(unsigned short*)&h2;
  __hip_bfloat16 h3 = __float2bfloat16(v.w); o.w = *(unsigned short*)&h3;
  *(ushort4*)d = o;
  float sacc = v.x * v.x + v.y * v.y + v.z * v.z + v.w * v.w;
  #pragma unroll
  for (int off = 32; off > 0; off >>= 1) sacc += __shfl_down(sacc, off);
  if ((tid & 63) == 0) cn[b * NC + row_base + r] = sacc;
}

// ---------------- pass 1: LDS-staged shared groups + MFMA + order-stat merge ----------------
#define INSERT_CANDS(ACC, CBASE)                                              \
  {                                                                           \
    const float4 cn4 = *(const float4*)&cnb[(CBASE) + lg * 4];                \
    unsigned k0, k1, k2, k3;                                                  \
    {                                                                         \
      unsigned kk[4];                                                         \
      _Pragma("unroll")                                                       \
      for (int r = 0; r < 4; ++r) {                                           \
        const float d2v = fmaf(-2.0f, (ACC)[r], ((const float*)&cn4)[r]);     \
        kk[r] = (__float_as_uint(d2v) & 0xFFFFE000u)                          \
                | (unsigned)((CBASE) + lg * 4 + r);                           \
      }                                                                       \
      unsigned t;                                                             \
      t = UMIN(kk[0], kk[1]); kk[1] = UMAX(kk[0], kk[1]); kk[0] = t;          \
      t = UMIN(kk[2], kk[3]); kk[3] = UMAX(kk[2], kk[3]); kk[2] = t;          \
      t = UMIN(kk[0], kk[2]); kk[2] = UMAX(kk[0], kk[2]); kk[0] = t;          \
      t = UMIN(kk[1], kk[3]); kk[3] = UMAX(kk[1], kk[3]); kk[1] = t;          \
      t = UMIN(kk[1], kk[2]); kk[2] = UMAX(kk[1], kk[2]); kk[1] = t;          \
      k0 = kk[0]; k1 = kk[1]; k2 = kk[2]; k3 = kk[3];                         \
    }                                                                         \
    unsigned nl[16];                                                          \
    nl[0] = UMIN(ld[0], k0);                                                  \
    nl[1] = UMIN(UMIN(ld[1], UMAX(ld[0], k0)), k1);                           \
    nl[2] = UMIN(UMIN(ld[2], UMAX(ld[1], k0)),                                \
                 UMIN(UMAX(ld[0], k1), k2));                                  \
    nl[3] = UMIN(UMIN(UMIN(ld[3], UMAX(ld[2], k0)),                           \
                      UMIN(UMAX(ld[1], k1), UMAX(ld[0], k2))), k3);           \
    _Pragma("unroll")                                                         \
    for (int i = 4; i < 16; ++i) {                                            \
      nl[i] = UMIN(UMIN(UMIN(ld[i], UMAX(ld[i - 1], k0)),                     \
                        UMIN(UMAX(ld[i - 2], k1), UMAX(ld[i - 3], k2))),      \
                   UMAX(ld[i - 4], k3));                                      \
    }                                                                         \
    _Pragma("unroll")                                                         \
    for (int i = 0; i < 16; ++i) ld[i] = nl[i];                               \
  }

#define MFMA_CHAIN(ACC, FRAGS)                                                \
  f32x4 ACC;                                                                  \
  {                                                                           \
    f32x4 c0_ = {0.f,0.f,0.f,0.f}, c1_ = {0.f,0.f,0.f,0.f};                   \
    f32x4 c2_ = {0.f,0.f,0.f,0.f}, c3_ = {0.f,0.f,0.f,0.f};                   \
    c0_ = __builtin_amdgcn_mfma_f32_16x16x32_bf16((FRAGS)[0], bfr[0], c0_, 0, 0, 0); \
    c1_ = __builtin_amdgcn_mfma_f32_16x16x32_bf16((FRAGS)[1], bfr[1], c1_, 0, 0, 0); \
    c2_ = __builtin_amdgcn_mfma_f32_16x16x32_bf16((FRAGS)[2], bfr[2], c2_, 0, 0, 0); \
    c3_ = __builtin_amdgcn_mfma_f32_16x16x32_bf16((FRAGS)[3], bfr[3], c3_, 0, 0, 0); \
    c0_ = __builtin_amdgcn_mfma_f32_16x16x32_bf16((FRAGS)[4], bfr[4], c0_, 0, 0, 0); \
    c1_ = __builtin_amdgcn_mfma_f32_16x16x32_bf16((FRAGS)[5], bfr[5], c1_, 0, 0, 0); \
    c2_ = __builtin_amdgcn_mfma_f32_16x16x32_bf16((FRAGS)[6], bfr[6], c2_, 0, 0, 0); \
    c3_ = __builtin_amdgcn_mfma_f32_16x16x32_bf16((FRAGS)[7], bfr[7], c3_, 0, 0, 0); \
    ACC = (c0_ + c1_) + (c2_ + c3_);                                          \
  }

// grid 512 = 4 batch x 8 split x 16 row-quads (64 rows/block, wave w = 16 rows).
// Split's 32 ctx groups staged to LDS in 16 chunks of 2 FULL groups (8 KB each;
// R16 bug was staging only half a group). Double-buffered; all 4 waves consume.
__global__ __launch_bounds__(256) void dist_topk_kernel(
    const __hip_bfloat16* __restrict__ qpb, const unsigned short* __restrict__ candb,
    const float* __restrict__ cn, unsigned* __restrict__ topidx)
{
  const int b = blockIdx.x & 3;
  const int split = (blockIdx.x >> 2) & 7;
  const int rq = blockIdx.x >> 5;          // 0..15
  const int tid = threadIdx.x;
  const int w = tid >> 6;                  // wave 0..3 -> row-tile
  const int lane = tid & 63;
  const int l15 = lane & 15;
  const int lg = lane >> 4;
  const int row0 = rq * 64 + w * 16;       // this wave's 16 rows

  __shared__ short sbuf[2][2][4096];       // 32 KB: [dbuf][group-in-chunk][full 8KB group]
  __shared__ unsigned md[4][16][4][17];    // 17.4 KB: [wave][row][list][entry]

  short8 bfr[8];
  {
    const short* qrow = (const short*)qpb + ((size_t)(b * S_ + row0 + l15)) * D_ + lg * 8;
    #pragma unroll
    for (int s = 0; s < 8; ++s) bfr[s] = *(const short8*)(qrow + s * 32);
  }

  const float* cnb = cn + b * NC;
  const short* cbase = (const short*)candb + (size_t)b * NC * D_;

  unsigned ld[16];
  #pragma unroll
  for (int i = 0; i < TOPN; ++i) ld[i] = 0xFFFFFFFFu;

  // stage chunk 0 (groups split + 8*{0,1}), FULL groups: 2 x short8 per group per thread
  short8 vS[2][2];
  #pragma unroll
  for (int i = 0; i < 2; ++i)
    #pragma unroll
    for (int h = 0; h < 2; ++h)
      vS[i][h] = *(const short8*)(cbase + (size_t)(split + 8 * i) * 4096 +
                                  h * 2048 + tid * 8);
  #pragma unroll
  for (int i = 0; i < 2; ++i)
    #pragma unroll
    for (int h = 0; h < 2; ++h)
      *(short8*)&sbuf[0][i][h * 2048 + tid * 8] = vS[i][h];

  #pragma unroll 1
  for (int c = 0; c < 16; ++c) {
    if (c < 15) {   // issue next chunk's global loads (complete during compute)
      #pragma unroll
      for (int i = 0; i < 2; ++i)
        #pragma unroll
        for (int h = 0; h < 2; ++h)
          vS[i][h] = *(const short8*)(cbase +
                       (size_t)(split + 8 * (2 * (c + 1) + i)) * 4096 +
                       h * 2048 + tid * 8);
    }
    __syncthreads();   // sbuf[c&1] published; prior readers of sbuf[(c+1)&1] done
    #pragma unroll
    for (int i = 0; i < 2; ++i) {
      short8 fr[8];
      #pragma unroll
      for (int s = 0; s < 8; ++s)
        fr[s] = *(const short8*)&sbuf[c & 1][i][s * 512 + lane * 8];
      MFMA_CHAIN(acc, fr);
      INSERT_CANDS(acc, (split + 8 * (2 * c + i)) * 16);
    }
    if (c < 15) {   // write next chunk to the other buffer (no reader overlap)
      #pragma unroll
      for (int i = 0; i < 2; ++i)
        #pragma unroll
        for (int h = 0; h < 2; ++h)
          *(short8*)&sbuf[(c + 1) & 1][i][h * 2048 + tid * 8] = vS[i][h];
    }
  }

  if (split < 4) {   // memory-candidate group 256+split (global path, 8 KB)
    const short* p = cbase + (size_t)(256 + split) * 4096 + lane * 8;
    short8 fr[8];
    #pragma unroll
    for (int s = 0; s < 8; ++s) fr[s] = *(const short8*)(p + s * 512);
    MFMA_CHAIN(acc, fr);
    INSERT_CANDS(acc, (256 + split) * 16);
  }

  // dump per-lane lists (4 lists per row within this wave's region)
  #pragma unroll
  for (int i = 0; i < TOPN; ++i) md[w][l15][lg][i] = ld[i];
  __syncthreads();

  // 4-way head-pointer merge: lane = r*4 + h; lane h captures ranks h,h+4,h+8,h+12
  {
    const int r = lane >> 2;
    const int h = lane & 3;
    int ptr = 0;
    unsigned cur = md[w][r][h][0];
    unsigned mk[4];
    #pragma unroll
    for (int it = 0; it < TOPN; ++it) {
      unsigned m = cur, o;
      o = __shfl_xor(m, 1, 4); m = o < m ? o : m;
      o = __shfl_xor(m, 2, 4); m = o < m ? o : m;
      if ((it & 3) == h) mk[it >> 2] = m;
      if (cur == m) {                 // unique winner (keys carry index) advances
        ++ptr;
        cur = (ptr < TOPN) ? md[w][r][h][ptr] : 0xFFFFFFFFu;
      }
    }
    unsigned* dst = topidx + ((size_t)(b * S_ + row0 + r)) * CANDK + split * TOPN;
    #pragma unroll
    for (int k2 = 0; k2 < 4; ++k2) dst[4 * k2 + h] = mk[k2];
  }
}

// ---------------- pass 2: dual key-presort -> select 32 -> fp64 refine -> bitonic top-16 ----------------
__global__ __launch_bounds__(256) void refine_kernel(
    const double* __restrict__ qp64, const float* __restrict__ ctx,
    const float* __restrict__ mem, const unsigned* __restrict__ topidx,
    float* __restrict__ out)
{
  const int row_global = blockIdx.x;
  const int tid = threadIdx.x;
  const int w = tid >> 6;
  const int lane = tid & 63;
  const int c2 = lane >> 5;
  const int ll = lane & 31;
  const int b = row_global >> 10;

  __shared__ unsigned sA[64], sB[64];
  __shared__ double d2s[64];
  __shared__ int    ids_s[64];

  if (w < 2) {
    unsigned key = topidx[(size_t)row_global * CANDK + w * 64 + lane];
    #pragma unroll
    for (int k = 2; k <= 64; k <<= 1) {
      #pragma unroll
      for (int j2 = k >> 1; j2 > 0; j2 >>= 1) {
        const unsigned o = __shfl_xor(key, j2);
        const bool up = ((lane & k) == 0);
        const bool keep_min = (((lane & j2) == 0) == up);
        const bool less = key < o;
        if (keep_min ? !less : less) key = o;
      }
    }
    if (w == 0) sA[lane] = key; else sB[lane] = key;
  }
  if (w == 2 && lane < 32) { d2s[32 + lane] = DBL_MAX; ids_s[32 + lane] = 0x7fffffff; }
  __syncthreads();

  const double* qrow = qp64 + (size_t)row_global * D_;
  double qd[8];
  #pragma unroll
  for (int t = 0; t < 8; t += 2) {
    double2 v = *(const double2*)&qrow[ll * 8 + t];
    qd[t] = v.x; qd[t + 1] = v.y;
  }

  int cis[4]; float4 cva[4], cvb[4];
  #pragma unroll
  for (int j = 0; j < 4; ++j) {
    const int p = w * 8 + 2 * j + c2;
    const unsigned kk = UMIN(sA[p], sB[31 - p]);
    cis[j] = (int)(kk & 0x1FFFu);
  }
  #pragma unroll
  for (int j = 0; j < 4; ++j) {
    const int ci = cis[j];
    const float* cp = (ci < C_) ? ctx + ((size_t)b * C_ + ci) * D_
                                : mem + ((size_t)b * K_ + (ci - C_)) * D_;
    cva[j] = *(const float4*)&cp[ll * 8];
    cvb[j] = *(const float4*)&cp[ll * 8 + 4];
  }

  #pragma unroll
  for (int j = 0; j < 4; ++j) {
    double a0 = 0.0, a1 = 0.0, df;
    df = qd[0] - (double)cva[j].x; a0 = fma(df, df, a0);
    df = qd[1] - (double)cva[j].y; a1 = fma(df, df, a1);
    df = qd[2] - (double)cva[j].z; a0 = fma(df, df, a0);
    df = qd[3] - (double)cva[j].w; a1 = fma(df, df, a1);
    df = qd[4] - (double)cvb[j].x; a0 = fma(df, df, a0);
    df = qd[5] - (double)cvb[j].y; a1 = fma(df, df, a1);
    df = qd[6] - (double)cvb[j].z; a0 = fma(df, df, a0);
    df = qd[7] - (double)cvb[j].w; a1 = fma(df, df, a1);
    double acc = a0 + a1;
    #pragma unroll
    for (int off = 16; off > 0; off >>= 1) acc += __shfl_down(acc, off, 32);
    if (ll == 0) { d2s[w * 8 + 2 * j + c2] = acc; ids_s[w * 8 + 2 * j + c2] = cis[j]; }
  }
  __syncthreads();

  if (w == 0) {
    double d2 = d2s[lane];
    int    ci = ids_s[lane];
    #pragma unroll
    for (int k = 2; k <= 64; k <<= 1) {
      #pragma unroll
      for (int j2 = k >> 1; j2 > 0; j2 >>= 1) {
        const double od2 = __shfl_xor(d2, j2);
        const int    oci = __shfl_xor(ci, j2);
        const bool up = ((lane & k) == 0);
        const bool less = (d2 < od2) || (d2 == od2 && ci < oci);
        const bool keep_min = (((lane & j2) == 0) == up);
        const bool take = keep_min ? !less : less;
        if (take) { d2 = od2; ci = oci; }
      }
    }
    if (lane < TOPN) {
      const size_t obase = (size_t)row_global * TOPN;
      out[obase + lane] = (float)sqrt(d2 < 0.0 ? 0.0 : d2);
      out[(size_t)B_ * S_ * TOPN + obase + lane] = (float)ci;
    }
  }
}

extern "C" void kernel_launch(void* const* d_in, const int* in_sizes, int n_in,
                              void* d_out, int out_size, void* d_ws, size_t ws_size,
                              hipStream_t stream) {
  const float* q    = (const float*)d_in[0];
  const float* ctx  = (const float*)d_in[1];
  const float* mem  = (const float*)d_in[2];
  const float* W    = (const float*)d_in[3];
  const float* bias = (const float*)d_in[4];
  float* out = (float*)d_out;

  double* qp64 = (double*)d_ws;                                             // 8 MB
  __hip_bfloat16* qpb = (__hip_bfloat16*)(qp64 + (size_t)B_ * S_ * D_);     // 2 MB
  unsigned short* candb = (unsigned short*)(qpb + (size_t)B_ * S_ * D_);    // 8.5 MB
  float* cn    = (float*)(candb + (size_t)B_ * NC * D_);                    // 66.5 KB
  unsigned* topidx = (unsigned*)(cn + (size_t)B_ * NC);                     // 2 MB

  prep_kernel<<<4672, 256, 0, stream>>>(q, W, bias, qp64, qpb, ctx, mem, candb, cn);
  dist_topk_kernel<<<512, 256, 0, stream>>>(qpb, candb, cn, topidx);
  refine_kernel<<<B_ * S_, 256, 0, stream>>>(qp64, ctx, mem, topidx, out);
}

// Round 18
// 78.353 us; speedup vs baseline: 1.9389x; 1.0025x over previous
//
#include <hip/hip_runtime.h>
#include <hip/hip_bf16.h>
#include <cfloat>
#include <cmath>

#define B_ 4
#define S_ 1024
#define C_ 4096
#define K_ 64
#define D_ 256
#define NC 4160   // C_ + K_  (= 260 groups of 16)
#define TOPN 16
#define NSPLIT 8
#define CANDK 128 // 8 splits x 16 keys; refine narrows to 32 by key

typedef __attribute__((ext_vector_type(8))) short short8;
typedef __attribute__((ext_vector_type(4))) float f32x4;

#define UMIN(a, b) ((a) < (b) ? (a) : (b))
#define UMAX(a, b) ((a) < (b) ? (b) : (a))

// ---------------- fused prep ----------------
// blocks 0..511:      projection (32x64 tiles, fp64)
// blocks 512..1535:   cvt/norm ctx — one block per 16-cand group, LDS-transposed,
//                     coalesced candb writes
// blocks 1536..1551:  cvt/norm mem (same scheme)
__global__ __launch_bounds__(256) void prep_kernel(
    const float* __restrict__ q, const float* __restrict__ W,
    const float* __restrict__ bias, double* __restrict__ qp64,
    __hip_bfloat16* __restrict__ qpb,
    const float* __restrict__ ctx, const float* __restrict__ mem,
    unsigned short* __restrict__ candb, float* __restrict__ cn)
{
  __shared__ alignas(16) float As[32][36];
  __shared__ alignas(16) float Ws[64][36];
  __shared__ alignas(16) unsigned short gbuf[4096];
  const int blk = blockIdx.x;
  const int tid = threadIdx.x;

  if (blk < 512) {   // ---- projection: 32 rows x 64 cols per block ----
    const int m0 = (blk >> 2) * 32;
    const int n0 = (blk & 3) * 64;
    const int tx = tid & 15;
    const int ty = tid >> 4;
    const int lr = tid >> 3;
    const int lk = (tid & 7) * 4;
    double acc[2][4] = {};
    for (int k0 = 0; k0 < D_; k0 += 32) {
      __syncthreads();
      {
        float4 a0 = *(const float4*)&q[(size_t)(m0 + lr) * D_ + k0 + lk];
        *(float4*)&As[lr][lk] = a0;
        float4 w0 = *(const float4*)&W[(size_t)(n0 + lr) * D_ + k0 + lk];
        float4 w1 = *(const float4*)&W[(size_t)(n0 + lr + 32) * D_ + k0 + lk];
        *(float4*)&Ws[lr][lk] = w0;
        *(float4*)&Ws[lr + 32][lk] = w1;
      }
      __syncthreads();
      #pragma unroll
      for (int kk = 0; kk < 32; kk += 4) {
        float4 av[2], wv[4];
        #pragma unroll
        for (int i = 0; i < 2; ++i) av[i] = *(const float4*)&As[ty * 2 + i][kk];
        #pragma unroll
        for (int j = 0; j < 4; ++j) wv[j] = *(const float4*)&Ws[tx + 16 * j][kk];
        #pragma unroll
        for (int i = 0; i < 2; ++i)
          #pragma unroll
          for (int j = 0; j < 4; ++j) {
            acc[i][j] = fma((double)av[i].x, (double)wv[j].x, acc[i][j]);
            acc[i][j] = fma((double)av[i].y, (double)wv[j].y, acc[i][j]);
            acc[i][j] = fma((double)av[i].z, (double)wv[j].z, acc[i][j]);
            acc[i][j] = fma((double)av[i].w, (double)wv[j].w, acc[i][j]);
          }
      }
    }
    #pragma unroll
    for (int i = 0; i < 2; ++i) {
      const int m = m0 + ty * 2 + i;
      #pragma unroll
      for (int j = 0; j < 4; ++j) {
        const int n = n0 + tx + 16 * j;
        const double v = acc[i][j] + (double)bias[n];
        qp64[(size_t)m * D_ + n] = v;
        qpb[(size_t)m * D_ + n] = __float2bfloat16((float)v);
      }
    }
    return;
  }

  // ---- cvt + norm: one block per full 16-candidate group ----
  const int gb = blk - 512;
  const float* src;
  int b2, dstg, norm_base;
  if (gb < 1024) {                 // ctx: b = gb>>8, group g = gb&255
    b2 = gb >> 8;
    const int g = gb & 255;
    src = ctx + ((size_t)b2 * C_ + (size_t)g * 16) * D_;
    dstg = g;
    norm_base = g * 16;
  } else {                         // mem: 16 blocks, 4 groups per batch
    const int j = gb - 1024;
    b2 = j >> 2;
    const int gl = j & 3;
    src = mem + ((size_t)b2 * K_ + (size_t)gl * 16) * D_;
    dstg = 256 + gl;
    norm_base = C_ + gl * 16;
  }
  // 1024 float4s (16 rows x 64), 4 per thread; wave w handles row 4c+w in chunk c
  #pragma unroll
  for (int c = 0; c < 4; ++c) {
    const int idx = c * 256 + tid;
    const int row = idx >> 6;          // = 4c + (tid>>6)
    const int k4 = idx & 63;
    const float4 v = ((const float4*)src)[idx];
    const int k = k4 * 4;
    const int s = k >> 5, lg2 = (k & 31) >> 3, ii = k & 7;
    ushort4 o;
    __hip_bfloat16 h0 = __float2bfloat16(v.x); o.x = *(unsigned short*)&h0;
    __hip_bfloat16 h1 = __float2bfloat16(v.y); o.y = *(unsigned short*)&h1;
    __hip_bfloat16 h2 = __float2bfloat16(v.z); o.z = *(unsigned short*)&h2;
    __hip_bfloat16 h3 = __float2bfloat16(v.w); o.w = *(unsigned short*)&h3;
    *(ushort4*)&gbuf[s * 512 + lg2 * 128 + (row & 15) * 8 + ii] = o;
    float sacc = v.x * v.x + v.y * v.y + v.z * v.z + v.w * v.w;
    #pragma unroll
    for (int off = 32; off > 0; off >>= 1) sacc += __shfl_down(sacc, off);
    if ((tid & 63) == 0) cn[b2 * NC + norm_base + row] = sacc;
  }
  __syncthreads();
  // coalesced write-out of the permuted 8 KB group
  unsigned short* dstp = candb + (size_t)b2 * (NC * D_) + (size_t)dstg * 4096;
  *(short8*)&dstp[tid * 8]        = *(const short8*)&gbuf[tid * 8];
  *(short8*)&dstp[2048 + tid * 8] = *(const short8*)&gbuf[2048 + tid * 8];
}

// ---------------- pass 1: LDS-staged shared groups + MFMA + order-stat merge ----------------
#define INSERT_CANDS(ACC, CBASE)                                              \
  {                                                                           \
    const float4 cn4 = *(const float4*)&cnb[(CBASE) + lg * 4];                \
    unsigned k0, k1, k2, k3;                                                  \
    {                                                                         \
      unsigned kk[4];                                                         \
      _Pragma("unroll")                                                       \
      for (int r = 0; r < 4; ++r) {                                           \
        const float d2v = fmaf(-2.0f, (ACC)[r], ((const float*)&cn4)[r]);     \
        kk[r] = (__float_as_uint(d2v) & 0xFFFFE000u)                          \
                | (unsigned)((CBASE) + lg * 4 + r);                           \
      }                                                                       \
      unsigned t;                                                             \
      t = UMIN(kk[0], kk[1]); kk[1] = UMAX(kk[0], kk[1]); kk[0] = t;          \
      t = UMIN(kk[2], kk[3]); kk[3] = UMAX(kk[2], kk[3]); kk[2] = t;          \
      t = UMIN(kk[0], kk[2]); kk[2] = UMAX(kk[0], kk[2]); kk[0] = t;          \
      t = UMIN(kk[1], kk[3]); kk[3] = UMAX(kk[1], kk[3]); kk[1] = t;          \
      t = UMIN(kk[1], kk[2]); kk[2] = UMAX(kk[1], kk[2]); kk[1] = t;          \
      k0 = kk[0]; k1 = kk[1]; k2 = kk[2]; k3 = kk[3];                         \
    }                                                                         \
    unsigned nl[16];                                                          \
    nl[0] = UMIN(ld[0], k0);                                                  \
    nl[1] = UMIN(UMIN(ld[1], UMAX(ld[0], k0)), k1);                           \
    nl[2] = UMIN(UMIN(ld[2], UMAX(ld[1], k0)),                                \
                 UMIN(UMAX(ld[0], k1), k2));                                  \
    nl[3] = UMIN(UMIN(UMIN(ld[3], UMAX(ld[2], k0)),                           \
                      UMIN(UMAX(ld[1], k1), UMAX(ld[0], k2))), k3);           \
    _Pragma("unroll")                                                         \
    for (int i = 4; i < 16; ++i) {                                            \
      nl[i] = UMIN(UMIN(UMIN(ld[i], UMAX(ld[i - 1], k0)),                     \
                        UMIN(UMAX(ld[i - 2], k1), UMAX(ld[i - 3], k2))),      \
                   UMAX(ld[i - 4], k3));                                      \
    }                                                                         \
    _Pragma("unroll")                                                         \
    for (int i = 0; i < 16; ++i) ld[i] = nl[i];                               \
  }

#define MFMA_CHAIN(ACC, FRAGS)                                                \
  f32x4 ACC;                                                                  \
  {                                                                           \
    f32x4 c0_ = {0.f,0.f,0.f,0.f}, c1_ = {0.f,0.f,0.f,0.f};                   \
    f32x4 c2_ = {0.f,0.f,0.f,0.f}, c3_ = {0.f,0.f,0.f,0.f};                   \
    c0_ = __builtin_amdgcn_mfma_f32_16x16x32_bf16((FRAGS)[0], bfr[0], c0_, 0, 0, 0); \
    c1_ = __builtin_amdgcn_mfma_f32_16x16x32_bf16((FRAGS)[1], bfr[1], c1_, 0, 0, 0); \
    c2_ = __builtin_amdgcn_mfma_f32_16x16x32_bf16((FRAGS)[2], bfr[2], c2_, 0, 0, 0); \
    c3_ = __builtin_amdgcn_mfma_f32_16x16x32_bf16((FRAGS)[3], bfr[3], c3_, 0, 0, 0); \
    c0_ = __builtin_amdgcn_mfma_f32_16x16x32_bf16((FRAGS)[4], bfr[4], c0_, 0, 0, 0); \
    c1_ = __builtin_amdgcn_mfma_f32_16x16x32_bf16((FRAGS)[5], bfr[5], c1_, 0, 0, 0); \
    c2_ = __builtin_amdgcn_mfma_f32_16x16x32_bf16((FRAGS)[6], bfr[6], c2_, 0, 0, 0); \
    c3_ = __builtin_amdgcn_mfma_f32_16x16x32_bf16((FRAGS)[7], bfr[7], c3_, 0, 0, 0); \
    ACC = (c0_ + c1_) + (c2_ + c3_);                                          \
  }

// grid 512 = 4 batch x 8 split x 16 row-quads (64 rows/block, wave w = 16 rows).
__global__ __launch_bounds__(256) void dist_topk_kernel(
    const __hip_bfloat16* __restrict__ qpb, const unsigned short* __restrict__ candb,
    const float* __restrict__ cn, unsigned* __restrict__ topidx)
{
  const int b = blockIdx.x & 3;
  const int split = (blockIdx.x >> 2) & 7;
  const int rq = blockIdx.x >> 5;          // 0..15
  const int tid = threadIdx.x;
  const int w = tid >> 6;                  // wave 0..3 -> row-tile
  const int lane = tid & 63;
  const int l15 = lane & 15;
  const int lg = lane >> 4;
  const int row0 = rq * 64 + w * 16;       // this wave's 16 rows

  __shared__ short sbuf[2][2][4096];       // 32 KB: [dbuf][group-in-chunk][full 8KB group]
  __shared__ unsigned md[4][16][4][17];    // 17.4 KB: [wave][row][list][entry]

  short8 bfr[8];
  {
    const short* qrow = (const short*)qpb + ((size_t)(b * S_ + row0 + l15)) * D_ + lg * 8;
    #pragma unroll
    for (int s = 0; s < 8; ++s) bfr[s] = *(const short8*)(qrow + s * 32);
  }

  const float* cnb = cn + b * NC;
  const short* cbase = (const short*)candb + (size_t)b * NC * D_;

  unsigned ld[16];
  #pragma unroll
  for (int i = 0; i < TOPN; ++i) ld[i] = 0xFFFFFFFFu;

  // stage chunk 0 (groups split + 8*{0,1}), FULL groups
  short8 vS[2][2];
  #pragma unroll
  for (int i = 0; i < 2; ++i)
    #pragma unroll
    for (int h = 0; h < 2; ++h)
      vS[i][h] = *(const short8*)(cbase + (size_t)(split + 8 * i) * 4096 +
                                  h * 2048 + tid * 8);
  #pragma unroll
  for (int i = 0; i < 2; ++i)
    #pragma unroll
    for (int h = 0; h < 2; ++h)
      *(short8*)&sbuf[0][i][h * 2048 + tid * 8] = vS[i][h];

  #pragma unroll 1
  for (int c = 0; c < 16; ++c) {
    if (c < 15) {   // issue next chunk's global loads (complete during compute)
      #pragma unroll
      for (int i = 0; i < 2; ++i)
        #pragma unroll
        for (int h = 0; h < 2; ++h)
          vS[i][h] = *(const short8*)(cbase +
                       (size_t)(split + 8 * (2 * (c + 1) + i)) * 4096 +
                       h * 2048 + tid * 8);
    }
    __syncthreads();   // sbuf[c&1] published; prior readers of sbuf[(c+1)&1] done
    #pragma unroll
    for (int i = 0; i < 2; ++i) {
      short8 fr[8];
      #pragma unroll
      for (int s = 0; s < 8; ++s)
        fr[s] = *(const short8*)&sbuf[c & 1][i][s * 512 + lane * 8];
      MFMA_CHAIN(acc, fr);
      INSERT_CANDS(acc, (split + 8 * (2 * c + i)) * 16);
    }
    if (c < 15) {   // write next chunk to the other buffer (no reader overlap)
      #pragma unroll
      for (int i = 0; i < 2; ++i)
        #pragma unroll
        for (int h = 0; h < 2; ++h)
          *(short8*)&sbuf[(c + 1) & 1][i][h * 2048 + tid * 8] = vS[i][h];
    }
  }

  if (split < 4) {   // memory-candidate group 256+split (global path, 8 KB)
    const short* p = cbase + (size_t)(256 + split) * 4096 + lane * 8;
    short8 fr[8];
    #pragma unroll
    for (int s = 0; s < 8; ++s) fr[s] = *(const short8*)(p + s * 512);
    MFMA_CHAIN(acc, fr);
    INSERT_CANDS(acc, (256 + split) * 16);
  }

  // dump per-lane lists (4 lists per row within this wave's region)
  #pragma unroll
  for (int i = 0; i < TOPN; ++i) md[w][l15][lg][i] = ld[i];
  __syncthreads();

  // 4-way head-pointer merge: lane = r*4 + h; lane h captures ranks h,h+4,h+8,h+12
  {
    const int r = lane >> 2;
    const int h = lane & 3;
    int ptr = 0;
    unsigned cur = md[w][r][h][0];
    unsigned mk[4];
    #pragma unroll
    for (int it = 0; it < TOPN; ++it) {
      unsigned m = cur, o;
      o = __shfl_xor(m, 1, 4); m = o < m ? o : m;
      o = __shfl_xor(m, 2, 4); m = o < m ? o : m;
      if ((it & 3) == h) mk[it >> 2] = m;
      if (cur == m) {                 // unique winner (keys carry index) advances
        ++ptr;
        cur = (ptr < TOPN) ? md[w][r][h][ptr] : 0xFFFFFFFFu;
      }
    }
    unsigned* dst = topidx + ((size_t)(b * S_ + row0 + r)) * CANDK + split * TOPN;
    #pragma unroll
    for (int k2 = 0; k2 < 4; ++k2) dst[4 * k2 + h] = mk[k2];
  }
}

// ---------------- pass 2: dual key-presort -> select 32 -> fp64 refine -> bitonic top-16 ----------------
__global__ __launch_bounds__(256) void refine_kernel(
    const double* __restrict__ qp64, const float* __restrict__ ctx,
    const float* __restrict__ mem, const unsigned* __restrict__ topidx,
    float* __restrict__ out)
{
  const int row_global = blockIdx.x;
  const int tid = threadIdx.x;
  const int w = tid >> 6;
  const int lane = tid & 63;
  const int c2 = lane >> 5;
  const int ll = lane & 31;
  const int b = row_global >> 10;

  __shared__ unsigned sA[64], sB[64];
  __shared__ double d2s[64];
  __shared__ int    ids_s[64];

  if (w < 2) {
    unsigned key = topidx[(size_t)row_global * CANDK + w * 64 + lane];
    #pragma unroll
    for (int k = 2; k <= 64; k <<= 1) {
      #pragma unroll
      for (int j2 = k >> 1; j2 > 0; j2 >>= 1) {
        const unsigned o = __shfl_xor(key, j2);
        const bool up = ((lane & k) == 0);
        const bool keep_min = (((lane & j2) == 0) == up);
        const bool less = key < o;
        if (keep_min ? !less : less) key = o;
      }
    }
    if (w == 0) sA[lane] = key; else sB[lane] = key;
  }
  if (w == 2 && lane < 32) { d2s[32 + lane] = DBL_MAX; ids_s[32 + lane] = 0x7fffffff; }
  __syncthreads();

  const double* qrow = qp64 + (size_t)row_global * D_;
  double qd[8];
  #pragma unroll
  for (int t = 0; t < 8; t += 2) {
    double2 v = *(const double2*)&qrow[ll * 8 + t];
    qd[t] = v.x; qd[t + 1] = v.y;
  }

  int cis[4]; float4 cva[4], cvb[4];
  #pragma unroll
  for (int j = 0; j < 4; ++j) {
    const int p = w * 8 + 2 * j + c2;
    const unsigned kk = UMIN(sA[p], sB[31 - p]);
    cis[j] = (int)(kk & 0x1FFFu);
  }
  #pragma unroll
  for (int j = 0; j < 4; ++j) {
    const int ci = cis[j];
    const float* cp = (ci < C_) ? ctx + ((size_t)b * C_ + ci) * D_
                                : mem + ((size_t)b * K_ + (ci - C_)) * D_;
    cva[j] = *(const float4*)&cp[ll * 8];
    cvb[j] = *(const float4*)&cp[ll * 8 + 4];
  }

  #pragma unroll
  for (int j = 0; j < 4; ++j) {
    double a0 = 0.0, a1 = 0.0, df;
    df = qd[0] - (double)cva[j].x; a0 = fma(df, df, a0);
    df = qd[1] - (double)cva[j].y; a1 = fma(df, df, a1);
    df = qd[2] - (double)cva[j].z; a0 = fma(df, df, a0);
    df = qd[3] - (double)cva[j].w; a1 = fma(df, df, a1);
    df = qd[4] - (double)cvb[j].x; a0 = fma(df, df, a0);
    df = qd[5] - (double)cvb[j].y; a1 = fma(df, df, a1);
    df = qd[6] - (double)cvb[j].z; a0 = fma(df, df, a0);
    df = qd[7] - (double)cvb[j].w; a1 = fma(df, df, a1);
    double acc = a0 + a1;
    #pragma unroll
    for (int off = 16; off > 0; off >>= 1) acc += __shfl_down(acc, off, 32);
    if (ll == 0) { d2s[w * 8 + 2 * j + c2] = acc; ids_s[w * 8 + 2 * j + c2] = cis[j]; }
  }
  __syncthreads();

  if (w == 0) {
    double d2 = d2s[lane];
    int    ci = ids_s[lane];
    #pragma unroll
    for (int k = 2; k <= 64; k <<= 1) {
      #pragma unroll
      for (int j2 = k >> 1; j2 > 0; j2 >>= 1) {
        const double od2 = __shfl_xor(d2, j2);
        const int    oci = __shfl_xor(ci, j2);
        const bool up = ((lane & k) == 0);
        const bool less = (d2 < od2) || (d2 == od2 && ci < oci);
        const bool keep_min = (((lane & j2) == 0) == up);
        const bool take = keep_min ? !less : less;
        if (take) { d2 = od2; ci = oci; }
      }
    }
    if (lane < TOPN) {
      const size_t obase = (size_t)row_global * TOPN;
      out[obase + lane] = (float)sqrt(d2 < 0.0 ? 0.0 : d2);
      out[(size_t)B_ * S_ * TOPN + obase + lane] = (float)ci;
    }
  }
}

extern "C" void kernel_launch(void* const* d_in, const int* in_sizes, int n_in,
                              void* d_out, int out_size, void* d_ws, size_t ws_size,
                              hipStream_t stream) {
  const float* q    = (const float*)d_in[0];
  const float* ctx  = (const float*)d_in[1];
  const float* mem  = (const float*)d_in[2];
  const float* W    = (const float*)d_in[3];
  const float* bias = (const float*)d_in[4];
  float* out = (float*)d_out;

  double* qp64 = (double*)d_ws;                                             // 8 MB
  __hip_bfloat16* qpb = (__hip_bfloat16*)(qp64 + (size_t)B_ * S_ * D_);     // 2 MB
  unsigned short* candb = (unsigned short*)(qpb + (size_t)B_ * S_ * D_);    // 8.5 MB
  float* cn    = (float*)(candb + (size_t)B_ * NC * D_);                    // 66.5 KB
  unsigned* topidx = (unsigned*)(cn + (size_t)B_ * NC);                     // 2 MB

  prep_kernel<<<1552, 256, 0, stream>>>(q, W, bias, qp64, qpb, ctx, mem, candb, cn);
  dist_topk_kernel<<<512, 256, 0, stream>>>(qpb, candb, cn, topidx);
  refine_kernel<<<B_ * S_, 256, 0, stream>>>(qp64, ctx, mem, topidx, out);
}